// Round 6
// baseline (1183.613 us; speedup 1.0000x reference)
//
#include <hip/hip_runtime.h>
#include <stdint.h>

// ---------------------------------------------------------------------------
// AttentionHead: Q/K/V projection + masked softmax attention + JAX-exact
// dropout (threefry2x32, key=42) + PV, with key-compaction (mask ~50% zeros).
//
// ROUND-5 RESULT: PRNG_VARIANT=1 failed absmax=1.06e-1 == dropout-noise
// magnitude (2*(1/1024)*(.3/.7)*Var(V) -> 5sigma ~ 0.1) => mask independent
// of reference, pipeline otherwise correct. Advancing tree to variant 2.
//
// FAILURE-ATTRIBUTION TREE:
//   absmax HUGE (>0.3) or NaN      -> set USE_COMPACTION 0 (suspect gather)
//   absmax MODERATE (~0.01-0.1)    -> advance PRNG_VARIANT: [1 DONE] 2 -> 0 -> 3
//   absmax tiny                    -> numerics tolerance, different diagnosis
//
// PRNG_VARIANT:
//   2 (current): partitionable, bits = o0^o1 of threefry((0,42),(0,n))
//                [partitionable 32-bit draw folds the 64-bit output via XOR]
//   1: partitionable truncation, bits = o1   [FAILED r5: absmax 1.06e-1]
//   0: legacy iota-split-in-half             (try 3rd)
//   3: partitionable with swapped counter words (try 4th)
#define PRNG_VARIANT 2
#define USE_COMPACTION 1
// ---------------------------------------------------------------------------

#define B_ 16
#define S_ 2048
#define D_ 1024
#define H_ 128
#define SCALE_ 0.08838834764831845f  /* 1/sqrt(128) */
#define KEEPP_ 0.7f

__device__ __forceinline__ void threefry2x32(uint32_t x0, uint32_t x1,
                                             uint32_t& o0, uint32_t& o1) {
  // key = (0, 42); ks2 = 0 ^ 42 ^ 0x1BD11BDA
  const uint32_t ks0 = 0u, ks1 = 42u, ks2 = 0x1BD11BF0u;
  x0 += ks0; x1 += ks1;
#define TF_R(r) { x0 += x1; x1 = (x1 << (r)) | (x1 >> (32 - (r))); x1 ^= x0; }
  TF_R(13) TF_R(15) TF_R(26) TF_R(6)
  x0 += ks1; x1 += ks2 + 1u;
  TF_R(17) TF_R(29) TF_R(16) TF_R(24)
  x0 += ks2; x1 += ks0 + 2u;
  TF_R(13) TF_R(15) TF_R(26) TF_R(6)
  x0 += ks0; x1 += ks1 + 3u;
  TF_R(17) TF_R(29) TF_R(16) TF_R(24)
  x0 += ks1; x1 += ks2 + 4u;
  TF_R(13) TF_R(15) TF_R(26) TF_R(6)
  x0 += ks2; x1 += ks0 + 5u;
#undef TF_R
  o0 = x0; o1 = x1;
}

__device__ __forceinline__ bool keep_rand(uint32_t n) {
  uint32_t o0, o1, bits;
#if PRNG_VARIANT == 1
  threefry2x32(0u, n, o0, o1);
  bits = o1;
#elif PRNG_VARIANT == 2
  threefry2x32(0u, n, o0, o1);
  bits = o0 ^ o1;               // partitionable 32-bit fold of (o0<<32)|o1
#elif PRNG_VARIANT == 3
  threefry2x32(n, 0u, o0, o1);
  bits = o0 ^ o1;
#else  // 0: legacy iota-split over 2^26 elements, half = 2^25
  if (n < (1u << 25)) { threefry2x32(n, n + (1u << 25), o0, o1); bits = o0; }
  else                { threefry2x32(n - (1u << 25), n, o0, o1); bits = o1; }
#endif
  // u = bitcast((bits>>9)|0x3F800000) - 1.0f  (exact, as in jax uniform)
  float u = __uint_as_float((bits >> 9) | 0x3F800000u) - 1.0f;
  return u < KEEPP_;
}

// ---------------------------------------------------------------------------
// Kernel 0: per-batch compaction of unmasked key indices.
// One wave (64 lanes) per batch; ballot+popcount scan over 32 chunks of 64.
// kidx[b][0:ncomp] = ascending original positions of mask==1; tail zeroed
// (poisoned ws must never become a row index).
// ---------------------------------------------------------------------------
__global__ __launch_bounds__(64) void mask_scan(
    const int* __restrict__ amask,
    int* __restrict__ kidx, int* __restrict__ ncomp) {
  const int b = blockIdx.x;
  const int lane = threadIdx.x;
  const int* m = amask + b * S_;
  int* outp = kidx + b * S_;
  int base = 0;
  for (int c = 0; c < S_; c += 64) {
    const int mv = m[c + lane];
    const unsigned long long bal = __ballot(mv != 0);
    const int off = __popcll(bal & ((1ull << lane) - 1ull));
    if (mv != 0) outp[base + off] = c + lane;
    base += (int)__popcll(bal);
  }
  if (lane == 0) ncomp[b] = base;
  for (int i = base + lane; i < S_; i += 64) outp[i] = 0;
}

// ---------------------------------------------------------------------------
// Kernel 1: qkv[m][0:128]=Q, [128:256]=K, [256:384]=V  (m = b*S + s)
// fp32 vector GEMM, tiles 64(M) x 64(N) x 32(K), 256 thr, 4x4 per thread.
// N-fragment rows mapped tx+16j -> 2-way LDS bank aliasing (free, m136).
// ---------------------------------------------------------------------------
__global__ __launch_bounds__(256) void qkv_proj(
    const float* __restrict__ x,
    const float* __restrict__ qw, const float* __restrict__ qb,
    const float* __restrict__ kw, const float* __restrict__ kb,
    const float* __restrict__ vw, const float* __restrict__ vb,
    float* __restrict__ qkv) {
  __shared__ float As[64][36];
  __shared__ float Bs[64][36];
  const int tid = threadIdx.x;
  const int m0 = blockIdx.x * 64;
  const int n0 = blockIdx.y * 64;

  const float* w; const float* bias;
  if (n0 < 128)      { w = qw; bias = qb; }
  else if (n0 < 256) { w = kw; bias = kb; }
  else               { w = vw; bias = vb; }
  const int nw = n0 & 127;

  const int ty = tid >> 4, tx = tid & 15;
  const int lr = tid >> 3;
  const int lc = (tid & 7) << 2;

  float acc[4][4];
#pragma unroll
  for (int i = 0; i < 4; ++i)
#pragma unroll
    for (int j = 0; j < 4; ++j) acc[i][j] = 0.f;

  const float* xA  = x + (size_t)(m0 + lr) * D_ + lc;
  const float* xA2 = xA + (size_t)32 * D_;
  const float* wB  = w + (size_t)(nw + lr) * D_ + lc;
  const float* wB2 = wB + (size_t)32 * D_;

  for (int k0 = 0; k0 < D_; k0 += 32) {
    *(float4*)&As[lr][lc]      = *(const float4*)(xA + k0);
    *(float4*)&As[lr + 32][lc] = *(const float4*)(xA2 + k0);
    *(float4*)&Bs[lr][lc]      = *(const float4*)(wB + k0);
    *(float4*)&Bs[lr + 32][lc] = *(const float4*)(wB2 + k0);
    __syncthreads();
#pragma unroll
    for (int kk = 0; kk < 32; kk += 4) {
      float4 a[4], bb[4];
#pragma unroll
      for (int i = 0; i < 4; ++i) a[i] = *(const float4*)&As[ty * 4 + i][kk];
#pragma unroll
      for (int j = 0; j < 4; ++j) bb[j] = *(const float4*)&Bs[tx + 16 * j][kk];
#pragma unroll
      for (int i = 0; i < 4; ++i)
#pragma unroll
        for (int j = 0; j < 4; ++j)
          acc[i][j] += a[i].x * bb[j].x + a[i].y * bb[j].y +
                       a[i].z * bb[j].z + a[i].w * bb[j].w;
    }
    __syncthreads();
  }

#pragma unroll
  for (int i = 0; i < 4; ++i) {
    float* orow = qkv + (size_t)(m0 + ty * 4 + i) * 384 + n0;
#pragma unroll
    for (int j = 0; j < 4; ++j)
      orow[tx + 16 * j] = acc[i][j] + bias[nw + tx + 16 * j];
  }
}

// ---------------------------------------------------------------------------
// Kernel 2: flash attention (USE_COMPACTION=1: over compacted keys, masked
// keys contribute exactly 0 to l and PV -> exclusion mathematically exact;
// =0: mask-based kill over all S_ keys — same body, kr degenerates to kt+tx).
// Block: 256 thr (= 16 row-groups x 16 lanes), 32 queries x key tiles of 32.
// Thread (ty,tx): scores for q in {2ty,2ty+1} x slots {kt+tx, kt+tx+16};
// PV accum for those q rows x head dims [8tx, 8tx+8).
// l accumulates PRE-dropout exp-sums; acc accumulates POST-dropout P @ V;
// out = acc / (l * 0.7). Dropout n uses the ORIGINAL key index.
// P broadcast within aligned 16-lane groups via __shfl(.,k,16); V read from
// global: vrow is wave-uniform -> one coalesced 512B row per step.
// LDS = Qs+Ks = 33.8 KB -> 4 blocks/CU (grid 1024 = 4/CU exact).
// ---------------------------------------------------------------------------
__global__ __launch_bounds__(256) void attn_fwd(
    const float* __restrict__ qkv,
    const int* __restrict__ amask,
    const int* __restrict__ kidx,
    const int* __restrict__ ncomp,
    float* __restrict__ out) {
  __shared__ float Qs[32][132];
  __shared__ float Ks[32][132];

  const int b   = blockIdx.y;
  const int q0  = blockIdx.x * 32;
  const int tid = threadIdx.x;
  const int ty = tid >> 4, tx = tid & 15;
#if USE_COMPACTION
  const int nc = ncomp[b];
  const int* kidx_b = kidx + b * S_;
  (void)amask;
#else
  const int nc = S_;
  const int* mrow = amask + b * S_;
  (void)kidx; (void)ncomp;
#endif

  // load Q tile, pre-scaled by 1/sqrt(H)
  const float* qbase = qkv + (size_t)(b * S_ + q0) * 384;
#pragma unroll
  for (int rep = 0; rep < 4; ++rep) {
    int idx = rep * 256 + tid;
    int r = idx >> 5, c4 = (idx & 31) << 2;
    float4 v = *(const float4*)(qbase + (size_t)r * 384 + c4);
    v.x *= SCALE_; v.y *= SCALE_; v.z *= SCALE_; v.w *= SCALE_;
    *(float4*)&Qs[r][c4] = v;
  }

  const int qr = ty * 2;
  const int hx = tx * 8;

  float acc0[8], acc1[8];
#pragma unroll
  for (int h = 0; h < 8; ++h) { acc0[h] = 0.f; acc1[h] = 0.f; }
  float m0v = -INFINITY, m1v = -INFINITY, l0 = 0.f, l1 = 0.f;

  // flat dropout index base: n = (b*S + q) * 2048 + k_orig, fits in u32
  const uint32_t nq0 = (uint32_t)(b * S_ + q0 + qr) << 11;
  const uint32_t nq1 = nq0 + (1u << 11);

  for (int kt = 0; kt < nc; kt += 32) {
    __syncthreads();  // prev tile's QK reads done -> safe to overwrite Ks
#pragma unroll
    for (int rep = 0; rep < 4; ++rep) {
      int idx = rep * 256 + tid;
      int r = idx >> 5, c4 = (idx & 31) << 2;
#if USE_COMPACTION
      int krow = kidx_b[kt + r];   // tail rows -> row 0, harmless (killed)
#else
      int krow = kt + r;
#endif
      *(float4*)&Ks[r][c4] =
          *(const float4*)(qkv + ((size_t)(b * S_ + krow) * 384 + 128) + c4);
    }
    const int j0 = kt + tx, j1 = j0 + 16;
#if USE_COMPACTION
    const int kr0 = kidx_b[j0];   // original key index (0 beyond nc)
    const int kr1 = kidx_b[j1];
    const bool kill0 = (j0 >= nc), kill1 = (j1 >= nc);
#else
    const int kr0 = j0, kr1 = j1;
    const bool kill0 = (mrow[j0] == 0), kill1 = (mrow[j1] == 0);
#endif
    __syncthreads();

    float s00 = 0.f, s01 = 0.f, s10 = 0.f, s11 = 0.f;
#pragma unroll 8
    for (int d = 0; d < 128; d += 4) {
      float4 qv0 = *(const float4*)&Qs[qr][d];
      float4 qv1 = *(const float4*)&Qs[qr + 1][d];
      float4 kv0 = *(const float4*)&Ks[tx][d];
      float4 kv1 = *(const float4*)&Ks[tx + 16][d];
      s00 += qv0.x * kv0.x + qv0.y * kv0.y + qv0.z * kv0.z + qv0.w * kv0.w;
      s01 += qv0.x * kv1.x + qv0.y * kv1.y + qv0.z * kv1.z + qv0.w * kv1.w;
      s10 += qv1.x * kv0.x + qv1.y * kv0.y + qv1.z * kv0.z + qv1.w * kv0.w;
      s11 += qv1.x * kv1.x + qv1.y * kv1.y + qv1.z * kv1.z + qv1.w * kv1.w;
    }
    if (kill0) { s00 = -INFINITY; s10 = -INFINITY; }
    if (kill1) { s01 = -INFINITY; s11 = -INFINITY; }

    float tm0 = fmaxf(s00, s01);
    float tm1 = fmaxf(s10, s11);
#pragma unroll
    for (int o = 1; o < 16; o <<= 1) {
      tm0 = fmaxf(tm0, __shfl_xor(tm0, o, 16));
      tm1 = fmaxf(tm1, __shfl_xor(tm1, o, 16));
    }
    float mn0 = fmaxf(m0v, tm0);
    float mn1 = fmaxf(m1v, tm1);

    // p: guard s==-inf (covers mn==-inf too); pre-dropout sums for l
    float p00 = (s00 == -INFINITY) ? 0.f : __expf(s00 - mn0);
    float p01 = (s01 == -INFINITY) ? 0.f : __expf(s01 - mn0);
    float p10 = (s10 == -INFINITY) ? 0.f : __expf(s10 - mn1);
    float p11 = (s11 == -INFINITY) ? 0.f : __expf(s11 - mn1);

    float ps0 = p00 + p01, ps1 = p10 + p11;
#pragma unroll
    for (int o = 1; o < 16; o <<= 1) {
      ps0 += __shfl_xor(ps0, o, 16);
      ps1 += __shfl_xor(ps1, o, 16);
    }

    // rescale; m==mn guard avoids exp(-inf - -inf)=NaN on all-masked prefix
    float r0 = (m0v == mn0) ? 1.f : __expf(m0v - mn0);
    float r1 = (m1v == mn1) ? 1.f : __expf(m1v - mn1);
    l0 = l0 * r0 + ps0;
    l1 = l1 * r1 + ps1;
#pragma unroll
    for (int h = 0; h < 8; ++h) { acc0[h] *= r0; acc1[h] *= r1; }
    m0v = mn0; m1v = mn1;

    // dropout in-register, keyed by ORIGINAL index (p==0 when killed -> d==0)
    float d00 = keep_rand(nq0 + (uint32_t)kr0) ? p00 : 0.f;
    float d01 = keep_rand(nq0 + (uint32_t)kr1) ? p01 : 0.f;
    float d10 = keep_rand(nq1 + (uint32_t)kr0) ? p10 : 0.f;
    float d11 = keep_rand(nq1 + (uint32_t)kr1) ? p11 : 0.f;

    // PV: P and V-row index broadcast via 16-wide shuffle; vrow is
    // wave-uniform (kr depends only on tx) -> coalesced 512B row reads.
    const float* vb_ = qkv + ((size_t)b * S_) * 384 + 256 + hx;
#pragma unroll 8
    for (int k = 0; k < 16; ++k) {
      float pa = __shfl(d00, k, 16);
      float pb = __shfl(d10, k, 16);
      int vrow = __shfl(kr0, k, 16);
      const float* vr = vb_ + (size_t)vrow * 384;
      float4 va  = *(const float4*)(vr);
      float4 vb2 = *(const float4*)(vr + 4);
      acc0[0] += pa * va.x;  acc0[1] += pa * va.y;
      acc0[2] += pa * va.z;  acc0[3] += pa * va.w;
      acc0[4] += pa * vb2.x; acc0[5] += pa * vb2.y;
      acc0[6] += pa * vb2.z; acc0[7] += pa * vb2.w;
      acc1[0] += pb * va.x;  acc1[1] += pb * va.y;
      acc1[2] += pb * va.z;  acc1[3] += pb * va.w;
      acc1[4] += pb * vb2.x; acc1[5] += pb * vb2.y;
      acc1[6] += pb * vb2.z; acc1[7] += pb * vb2.w;
    }
#pragma unroll 8
    for (int k = 0; k < 16; ++k) {
      float pa = __shfl(d01, k, 16);
      float pb = __shfl(d11, k, 16);
      int vrow = __shfl(kr1, k, 16);
      const float* vr = vb_ + (size_t)vrow * 384;
      float4 va  = *(const float4*)(vr);
      float4 vb2 = *(const float4*)(vr + 4);
      acc0[0] += pa * va.x;  acc0[1] += pa * va.y;
      acc0[2] += pa * va.z;  acc0[3] += pa * va.w;
      acc0[4] += pa * vb2.x; acc0[5] += pa * vb2.y;
      acc0[6] += pa * vb2.z; acc0[7] += pa * vb2.w;
      acc1[0] += pb * va.x;  acc1[1] += pb * va.y;
      acc1[2] += pb * va.z;  acc1[3] += pb * va.w;
      acc1[4] += pb * vb2.x; acc1[5] += pb * vb2.y;
      acc1[6] += pb * vb2.z; acc1[7] += pb * vb2.w;
    }
  }

  const float inv0 = 1.0f / (l0 * KEEPP_);
  const float inv1 = 1.0f / (l1 * KEEPP_);
  float* o0 = out + (size_t)(b * S_ + q0 + qr) * H_ + hx;
  float* o1 = o0 + H_;
  float4 w0 = make_float4(acc0[0] * inv0, acc0[1] * inv0, acc0[2] * inv0, acc0[3] * inv0);
  float4 w1 = make_float4(acc0[4] * inv0, acc0[5] * inv0, acc0[6] * inv0, acc0[7] * inv0);
  float4 w2 = make_float4(acc1[0] * inv1, acc1[1] * inv1, acc1[2] * inv1, acc1[3] * inv1);
  float4 w3 = make_float4(acc1[4] * inv1, acc1[5] * inv1, acc1[6] * inv1, acc1[7] * inv1);
  *(float4*)(o0)     = w0;
  *(float4*)(o0 + 4) = w1;
  *(float4*)(o1)     = w2;
  *(float4*)(o1 + 4) = w3;
}

// ---------------------------------------------------------------------------
extern "C" void kernel_launch(void* const* d_in, const int* in_sizes, int n_in,
                              void* d_out, int out_size, void* d_ws, size_t ws_size,
                              hipStream_t stream) {
  (void)in_sizes; (void)n_in; (void)out_size; (void)ws_size;
  const float* x  = (const float*)d_in[0];
  const int* am   = (const int*)d_in[1];
  const float* qw = (const float*)d_in[2];
  const float* qb = (const float*)d_in[3];
  const float* kw = (const float*)d_in[4];
  const float* kb = (const float*)d_in[5];
  const float* vw = (const float*)d_in[6];
  const float* vb = (const float*)d_in[7];
  float* out = (float*)d_out;

  // ws layout: qkv (48MB) | kidx (16*2048*4) | ncomp (16*4)
  float* qkv = (float*)d_ws;
  int* kidx  = (int*)((char*)d_ws + (size_t)B_ * S_ * 384 * 4);
  int* ncomp = kidx + B_ * S_;

#if USE_COMPACTION
  mask_scan<<<B_, 64, 0, stream>>>(am, kidx, ncomp);
#endif
  qkv_proj<<<dim3((B_ * S_) / 64, 384 / 64), 256, 0, stream>>>(
      x, qw, qb, kw, kb, vw, vb, qkv);
  attn_fwd<<<dim3(S_ / 32, B_), 256, 0, stream>>>(qkv, am, kidx, ncomp, out);
}

// Round 8
// 847.219 us; speedup vs baseline: 1.3971x; 1.3971x over previous
//
#include <hip/hip_runtime.h>
#include <stdint.h>

// ---------------------------------------------------------------------------
// AttentionHead: Q/K/V projection (bf16x3 MFMA) + masked softmax attention +
// JAX-exact dropout (threefry2x32, key=42) + PV, with key-compaction.
//
// ROUND-6: PASSED (fp32 qkv), absmax 4.9e-4, total 1184 us (attn 597, qkv ~575).
// ROUND-7: qkv -> bf16x3 MFMA; bench TIMED OUT (no GPU). ROUND-8: resubmit
// unchanged after audit (alignment/layout/banks/barriers all check out).
// attn_fwd byte-identical to the r6 PASS -> any validation delta attributes
// to the MFMA path.
//
// MFMA layout (guide §3, m89/m156-verified):
//   mfma_f32_16x16x32_bf16: D/C row=(l>>4)*4+reg, col=l&15; A m=l&15,
//   B n=l&15, K grouped by l>>4 (4+4 split across two K=16 halves).
//   A/B loaded with the SAME lane->k convention => any k-permutation
//   mismatch vs HW cancels in the full-K sum (robustness argument).
#define PRNG_VARIANT 2
#define USE_COMPACTION 1
// ---------------------------------------------------------------------------

#define B_ 16
#define S_ 2048
#define D_ 1024
#define H_ 128
#define SCALE_ 0.08838834764831845f  /* 1/sqrt(128) */
#define KEEPP_ 0.7f

typedef __attribute__((ext_vector_type(8))) short bf16x8_t;
typedef __attribute__((ext_vector_type(4))) float f32x4_t;

__device__ __forceinline__ void threefry2x32(uint32_t x0, uint32_t x1,
                                             uint32_t& o0, uint32_t& o1) {
  // key = (0, 42); ks2 = 0 ^ 42 ^ 0x1BD11BDA
  const uint32_t ks0 = 0u, ks1 = 42u, ks2 = 0x1BD11BF0u;
  x0 += ks0; x1 += ks1;
#define TF_R(r) { x0 += x1; x1 = (x1 << (r)) | (x1 >> (32 - (r))); x1 ^= x0; }
  TF_R(13) TF_R(15) TF_R(26) TF_R(6)
  x0 += ks1; x1 += ks2 + 1u;
  TF_R(17) TF_R(29) TF_R(16) TF_R(24)
  x0 += ks2; x1 += ks0 + 2u;
  TF_R(13) TF_R(15) TF_R(26) TF_R(6)
  x0 += ks0; x1 += ks1 + 3u;
  TF_R(17) TF_R(29) TF_R(16) TF_R(24)
  x0 += ks1; x1 += ks2 + 4u;
  TF_R(13) TF_R(15) TF_R(26) TF_R(6)
  x0 += ks2; x1 += ks0 + 5u;
#undef TF_R
  o0 = x0; o1 = x1;
}

__device__ __forceinline__ bool keep_rand(uint32_t n) {
  uint32_t o0, o1, bits;
#if PRNG_VARIANT == 2
  threefry2x32(0u, n, o0, o1);
  bits = o0 ^ o1;               // partitionable 32-bit fold (VERIFIED r6 pass)
#elif PRNG_VARIANT == 1
  threefry2x32(0u, n, o0, o1);
  bits = o1;                    // FAILED r5: absmax 1.06e-1
#else
  if (n < (1u << 25)) { threefry2x32(n, n + (1u << 25), o0, o1); bits = o0; }
  else                { threefry2x32(n - (1u << 25), n, o0, o1); bits = o1; }
#endif
  float u = __uint_as_float((bits >> 9) | 0x3F800000u) - 1.0f;
  return u < KEEPP_;
}

// round-to-nearest-even fp32 -> bf16 (finite inputs)
__device__ __forceinline__ uint16_t bf16_rne(float f) {
  uint32_t u = __float_as_uint(f);
  return (uint16_t)((u + 0x7FFFu + ((u >> 16) & 1u)) >> 16);
}

// ---------------------------------------------------------------------------
// Kernel 0: per-batch compaction of unmasked key indices (unchanged).
// ---------------------------------------------------------------------------
__global__ __launch_bounds__(64) void mask_scan(
    const int* __restrict__ amask,
    int* __restrict__ kidx, int* __restrict__ ncomp) {
  const int b = blockIdx.x;
  const int lane = threadIdx.x;
  const int* m = amask + b * S_;
  int* outp = kidx + b * S_;
  int base = 0;
  for (int c = 0; c < S_; c += 64) {
    const int mv = m[c + lane];
    const unsigned long long bal = __ballot(mv != 0);
    const int off = __popcll(bal & ((1ull << lane) - 1ull));
    if (mv != 0) outp[base + off] = c + lane;
    base += (int)__popcll(bal);
  }
  if (lane == 0) ncomp[b] = base;
  for (int i = base + lane; i < S_; i += 64) outp[i] = 0;
}

// ---------------------------------------------------------------------------
// Kernel 1: qkv projection via bf16x3 MFMA.
// C = X * W^T (+bias), X [32768][1024] fp32, W-panel [128][1024] fp32.
// Split X=Xh+Xl, W=Wh+Wl (bf16); C ~= Xh*Wh + Xh*Wl + Xl*Wh (lo*lo dropped,
// ~2^-18 relative -> ~1e-5 abs, far under threshold).
// Block 256 thr = 4 waves (2x2), tile 128(M) x 128(N), BK=32.
// Inline f32->bf16 hi/lo conversion during LDS staging (no extra ws needed).
// LDS 4x[128][36] ushort = 36 KB -> 4 blocks/CU. Grid (256, 3) panels Q,K,V.
// Frag reads: dword-stride 18/row -> 16 lanes hit 16 distinct even bank
// pairs (covers all 32 banks) = wave64 minimum aliasing, ~conflict-free.
// ---------------------------------------------------------------------------
__device__ __forceinline__ bf16x8_t ld_frag(const ushort T[128][36], int row, int g) {
  union { uint2 d[2]; bf16x8_t v; } u;
  u.d[0] = *(const uint2*)&T[row][g << 2];          // k-half 0: k = 4g..4g+3
  u.d[1] = *(const uint2*)&T[row][16 + (g << 2)];   // k-half 1: k = 16+4g..
  return u.v;
}

__global__ __launch_bounds__(256) void qkv_mfma(
    const float* __restrict__ x,
    const float* __restrict__ qw, const float* __restrict__ qb,
    const float* __restrict__ kw, const float* __restrict__ kb,
    const float* __restrict__ vw, const float* __restrict__ vb,
    float* __restrict__ qkv) {
  __shared__ ushort Xh[128][36], Xl[128][36], Wh[128][36], Wl[128][36];

  const int tid = threadIdx.x;
  const int m0  = blockIdx.x * 128;
  const int by  = blockIdx.y;                       // 0=Q, 1=K, 2=V panel
  const float* wsrc = (by == 0) ? qw : (by == 1) ? kw : vw;
  const float* bias = (by == 0) ? qb : (by == 1) ? kb : vb;

  const int wid = tid >> 6, lane = tid & 63;
  const int wy = wid >> 1, wx = wid & 1;            // 2x2 wave grid
  const int lm = lane & 15, g = lane >> 4;

  // staging mapping: 4 iters x 256 thr cover 128 rows x 8 float4
  const int srow = tid >> 3;
  const int sc4  = (tid & 7) << 2;

  f32x4_t acc[4][4];
#pragma unroll
  for (int i = 0; i < 4; ++i)
#pragma unroll
    for (int j = 0; j < 4; ++j) acc[i][j] = (f32x4_t){0.f, 0.f, 0.f, 0.f};

  for (int k0 = 0; k0 < D_; k0 += 32) {
    __syncthreads();
#pragma unroll
    for (int i = 0; i < 4; ++i) {
      const int row = srow + (i << 5);              // +32 rows per iter
      {
        float4 v = *(const float4*)(x + (size_t)(m0 + row) * D_ + k0 + sc4);
        uint16_t h0 = bf16_rne(v.x), h1 = bf16_rne(v.y),
                 h2 = bf16_rne(v.z), h3 = bf16_rne(v.w);
        float r0 = v.x - __uint_as_float((uint32_t)h0 << 16);
        float r1 = v.y - __uint_as_float((uint32_t)h1 << 16);
        float r2 = v.z - __uint_as_float((uint32_t)h2 << 16);
        float r3 = v.w - __uint_as_float((uint32_t)h3 << 16);
        *(uint2*)&Xh[row][sc4] = make_uint2((uint32_t)h0 | ((uint32_t)h1 << 16),
                                            (uint32_t)h2 | ((uint32_t)h3 << 16));
        *(uint2*)&Xl[row][sc4] = make_uint2(
            (uint32_t)bf16_rne(r0) | ((uint32_t)bf16_rne(r1) << 16),
            (uint32_t)bf16_rne(r2) | ((uint32_t)bf16_rne(r3) << 16));
      }
      {
        float4 v = *(const float4*)(wsrc + (size_t)row * D_ + k0 + sc4);
        uint16_t h0 = bf16_rne(v.x), h1 = bf16_rne(v.y),
                 h2 = bf16_rne(v.z), h3 = bf16_rne(v.w);
        float r0 = v.x - __uint_as_float((uint32_t)h0 << 16);
        float r1 = v.y - __uint_as_float((uint32_t)h1 << 16);
        float r2 = v.z - __uint_as_float((uint32_t)h2 << 16);
        float r3 = v.w - __uint_as_float((uint32_t)h3 << 16);
        *(uint2*)&Wh[row][sc4] = make_uint2((uint32_t)h0 | ((uint32_t)h1 << 16),
                                            (uint32_t)h2 | ((uint32_t)h3 << 16));
        *(uint2*)&Wl[row][sc4] = make_uint2(
            (uint32_t)bf16_rne(r0) | ((uint32_t)bf16_rne(r1) << 16),
            (uint32_t)bf16_rne(r2) | ((uint32_t)bf16_rne(r3) << 16));
      }
    }
    __syncthreads();

    bf16x8_t Ah[4], Al[4], Bh[4], Bl[4];
#pragma unroll
    for (int mi = 0; mi < 4; ++mi) {
      const int r = (wy << 6) + (mi << 4) + lm;
      Ah[mi] = ld_frag(Xh, r, g);
      Al[mi] = ld_frag(Xl, r, g);
    }
#pragma unroll
    for (int ni = 0; ni < 4; ++ni) {
      const int r = (wx << 6) + (ni << 4) + lm;
      Bh[ni] = ld_frag(Wh, r, g);
      Bl[ni] = ld_frag(Wl, r, g);
    }
#pragma unroll
    for (int mi = 0; mi < 4; ++mi)
#pragma unroll
      for (int ni = 0; ni < 4; ++ni) {
        acc[mi][ni] = __builtin_amdgcn_mfma_f32_16x16x32_bf16(
            Ah[mi], Bh[ni], acc[mi][ni], 0, 0, 0);
        acc[mi][ni] = __builtin_amdgcn_mfma_f32_16x16x32_bf16(
            Ah[mi], Bl[ni], acc[mi][ni], 0, 0, 0);
        acc[mi][ni] = __builtin_amdgcn_mfma_f32_16x16x32_bf16(
            Al[mi], Bh[ni], acc[mi][ni], 0, 0, 0);
      }
  }

  // epilogue: D row=(l>>4)*4+reg, col=l&15 (m89-verified layout)
#pragma unroll
  for (int mi = 0; mi < 4; ++mi) {
    const int row = m0 + (wy << 6) + (mi << 4) + (g << 2);
#pragma unroll
    for (int ni = 0; ni < 4; ++ni) {
      const int nl = (wx << 6) + (ni << 4) + lm;    // n-local in 0..127
      const float bv = bias[nl];
#pragma unroll
      for (int r = 0; r < 4; ++r)
        qkv[(size_t)(row + r) * 384 + (by << 7) + nl] = acc[mi][ni][r] + bv;
    }
  }
}

// ---------------------------------------------------------------------------
// Kernel 2: flash attention over compacted keys (UNCHANGED from round-6 PASS).
// ---------------------------------------------------------------------------
__global__ __launch_bounds__(256) void attn_fwd(
    const float* __restrict__ qkv,
    const int* __restrict__ amask,
    const int* __restrict__ kidx,
    const int* __restrict__ ncomp,
    float* __restrict__ out) {
  __shared__ float Qs[32][132];
  __shared__ float Ks[32][132];

  const int b   = blockIdx.y;
  const int q0  = blockIdx.x * 32;
  const int tid = threadIdx.x;
  const int ty = tid >> 4, tx = tid & 15;
#if USE_COMPACTION
  const int nc = ncomp[b];
  const int* kidx_b = kidx + b * S_;
  (void)amask;
#else
  const int nc = S_;
  const int* mrow = amask + b * S_;
  (void)kidx; (void)ncomp;
#endif

  const float* qbase = qkv + (size_t)(b * S_ + q0) * 384;
#pragma unroll
  for (int rep = 0; rep < 4; ++rep) {
    int idx = rep * 256 + tid;
    int r = idx >> 5, c4 = (idx & 31) << 2;
    float4 v = *(const float4*)(qbase + (size_t)r * 384 + c4);
    v.x *= SCALE_; v.y *= SCALE_; v.z *= SCALE_; v.w *= SCALE_;
    *(float4*)&Qs[r][c4] = v;
  }

  const int qr = ty * 2;
  const int hx = tx * 8;

  float acc0[8], acc1[8];
#pragma unroll
  for (int h = 0; h < 8; ++h) { acc0[h] = 0.f; acc1[h] = 0.f; }
  float m0v = -INFINITY, m1v = -INFINITY, l0 = 0.f, l1 = 0.f;

  const uint32_t nq0 = (uint32_t)(b * S_ + q0 + qr) << 11;
  const uint32_t nq1 = nq0 + (1u << 11);

  for (int kt = 0; kt < nc; kt += 32) {
    __syncthreads();
#pragma unroll
    for (int rep = 0; rep < 4; ++rep) {
      int idx = rep * 256 + tid;
      int r = idx >> 5, c4 = (idx & 31) << 2;
#if USE_COMPACTION
      int krow = kidx_b[kt + r];
#else
      int krow = kt + r;
#endif
      *(float4*)&Ks[r][c4] =
          *(const float4*)(qkv + ((size_t)(b * S_ + krow) * 384 + 128) + c4);
    }
    const int j0 = kt + tx, j1 = j0 + 16;
#if USE_COMPACTION
    const int kr0 = kidx_b[j0];
    const int kr1 = kidx_b[j1];
    const bool kill0 = (j0 >= nc), kill1 = (j1 >= nc);
#else
    const int kr0 = j0, kr1 = j1;
    const bool kill0 = (mrow[j0] == 0), kill1 = (mrow[j1] == 0);
#endif
    __syncthreads();

    float s00 = 0.f, s01 = 0.f, s10 = 0.f, s11 = 0.f;
#pragma unroll 8
    for (int d = 0; d < 128; d += 4) {
      float4 qv0 = *(const float4*)&Qs[qr][d];
      float4 qv1 = *(const float4*)&Qs[qr + 1][d];
      float4 kv0 = *(const float4*)&Ks[tx][d];
      float4 kv1 = *(const float4*)&Ks[tx + 16][d];
      s00 += qv0.x * kv0.x + qv0.y * kv0.y + qv0.z * kv0.z + qv0.w * kv0.w;
      s01 += qv0.x * kv1.x + qv0.y * kv1.y + qv0.z * kv1.z + qv0.w * kv1.w;
      s10 += qv1.x * kv0.x + qv1.y * kv0.y + qv1.z * kv0.z + qv1.w * kv0.w;
      s11 += qv1.x * kv1.x + qv1.y * kv1.y + qv1.z * kv1.z + qv1.w * kv1.w;
    }
    if (kill0) { s00 = -INFINITY; s10 = -INFINITY; }
    if (kill1) { s01 = -INFINITY; s11 = -INFINITY; }

    float tm0 = fmaxf(s00, s01);
    float tm1 = fmaxf(s10, s11);
#pragma unroll
    for (int o = 1; o < 16; o <<= 1) {
      tm0 = fmaxf(tm0, __shfl_xor(tm0, o, 16));
      tm1 = fmaxf(tm1, __shfl_xor(tm1, o, 16));
    }
    float mn0 = fmaxf(m0v, tm0);
    float mn1 = fmaxf(m1v, tm1);

    float p00 = (s00 == -INFINITY) ? 0.f : __expf(s00 - mn0);
    float p01 = (s01 == -INFINITY) ? 0.f : __expf(s01 - mn0);
    float p10 = (s10 == -INFINITY) ? 0.f : __expf(s10 - mn1);
    float p11 = (s11 == -INFINITY) ? 0.f : __expf(s11 - mn1);

    float ps0 = p00 + p01, ps1 = p10 + p11;
#pragma unroll
    for (int o = 1; o < 16; o <<= 1) {
      ps0 += __shfl_xor(ps0, o, 16);
      ps1 += __shfl_xor(ps1, o, 16);
    }

    float r0 = (m0v == mn0) ? 1.f : __expf(m0v - mn0);
    float r1 = (m1v == mn1) ? 1.f : __expf(m1v - mn1);
    l0 = l0 * r0 + ps0;
    l1 = l1 * r1 + ps1;
#pragma unroll
    for (int h = 0; h < 8; ++h) { acc0[h] *= r0; acc1[h] *= r1; }
    m0v = mn0; m1v = mn1;

    float d00 = keep_rand(nq0 + (uint32_t)kr0) ? p00 : 0.f;
    float d01 = keep_rand(nq0 + (uint32_t)kr1) ? p01 : 0.f;
    float d10 = keep_rand(nq1 + (uint32_t)kr0) ? p10 : 0.f;
    float d11 = keep_rand(nq1 + (uint32_t)kr1) ? p11 : 0.f;

    const float* vb_ = qkv + ((size_t)b * S_) * 384 + 256 + hx;
#pragma unroll 8
    for (int k = 0; k < 16; ++k) {
      float pa = __shfl(d00, k, 16);
      float pb = __shfl(d10, k, 16);
      int vrow = __shfl(kr0, k, 16);
      const float* vr = vb_ + (size_t)vrow * 384;
      float4 va  = *(const float4*)(vr);
      float4 vb2 = *(const float4*)(vr + 4);
      acc0[0] += pa * va.x;  acc0[1] += pa * va.y;
      acc0[2] += pa * va.z;  acc0[3] += pa * va.w;
      acc0[4] += pa * vb2.x; acc0[5] += pa * vb2.y;
      acc0[6] += pa * vb2.z; acc0[7] += pa * vb2.w;
      acc1[0] += pb * va.x;  acc1[1] += pb * va.y;
      acc1[2] += pb * va.z;  acc1[3] += pb * va.w;
      acc1[4] += pb * vb2.x; acc1[5] += pb * vb2.y;
      acc1[6] += pb * vb2.z; acc1[7] += pb * vb2.w;
    }
#pragma unroll 8
    for (int k = 0; k < 16; ++k) {
      float pa = __shfl(d01, k, 16);
      float pb = __shfl(d11, k, 16);
      int vrow = __shfl(kr1, k, 16);
      const float* vr = vb_ + (size_t)vrow * 384;
      float4 va  = *(const float4*)(vr);
      float4 vb2 = *(const float4*)(vr + 4);
      acc0[0] += pa * va.x;  acc0[1] += pa * va.y;
      acc0[2] += pa * va.z;  acc0[3] += pa * va.w;
      acc0[4] += pa * vb2.x; acc0[5] += pa * vb2.y;
      acc0[6] += pa * vb2.z; acc0[7] += pa * vb2.w;
      acc1[0] += pb * va.x;  acc1[1] += pb * va.y;
      acc1[2] += pb * va.z;  acc1[3] += pb * va.w;
      acc1[4] += pb * vb2.x; acc1[5] += pb * vb2.y;
      acc1[6] += pb * vb2.z; acc1[7] += pb * vb2.w;
    }
  }

  const float inv0 = 1.0f / (l0 * KEEPP_);
  const float inv1 = 1.0f / (l1 * KEEPP_);
  float* o0 = out + (size_t)(b * S_ + q0 + qr) * H_ + hx;
  float* o1 = o0 + H_;
  float4 w0 = make_float4(acc0[0] * inv0, acc0[1] * inv0, acc0[2] * inv0, acc0[3] * inv0);
  float4 w1 = make_float4(acc0[4] * inv0, acc0[5] * inv0, acc0[6] * inv0, acc0[7] * inv0);
  float4 w2 = make_float4(acc1[0] * inv1, acc1[1] * inv1, acc1[2] * inv1, acc1[3] * inv1);
  float4 w3 = make_float4(acc1[4] * inv1, acc1[5] * inv1, acc1[6] * inv1, acc1[7] * inv1);
  *(float4*)(o0)     = w0;
  *(float4*)(o0 + 4) = w1;
  *(float4*)(o1)     = w2;
  *(float4*)(o1 + 4) = w3;
}

// ---------------------------------------------------------------------------
extern "C" void kernel_launch(void* const* d_in, const int* in_sizes, int n_in,
                              void* d_out, int out_size, void* d_ws, size_t ws_size,
                              hipStream_t stream) {
  (void)in_sizes; (void)n_in; (void)out_size; (void)ws_size;
  const float* x  = (const float*)d_in[0];
  const int* am   = (const int*)d_in[1];
  const float* qw = (const float*)d_in[2];
  const float* qb = (const float*)d_in[3];
  const float* kw = (const float*)d_in[4];
  const float* kb = (const float*)d_in[5];
  const float* vw = (const float*)d_in[6];
  const float* vb = (const float*)d_in[7];
  float* out = (float*)d_out;

  // ws layout: qkv (48MB) | kidx (16*2048*4) | ncomp (16*4)
  float* qkv = (float*)d_ws;
  int* kidx  = (int*)((char*)d_ws + (size_t)B_ * S_ * 384 * 4);
  int* ncomp = kidx + B_ * S_;

#if USE_COMPACTION
  mask_scan<<<B_, 64, 0, stream>>>(am, kidx, ncomp);
#endif
  qkv_mfma<<<dim3((B_ * S_) / 128, 3), 256, 0, stream>>>(
      x, qw, qb, kw, kb, vw, vb, qkv);
  attn_fwd<<<dim3(S_ / 32, B_), 256, 0, stream>>>(qkv, am, kidx, ncomp, out);
}

// Round 9
// 533.545 us; speedup vs baseline: 2.2184x; 1.5879x over previous
//
#include <hip/hip_runtime.h>
#include <stdint.h>

// ---------------------------------------------------------------------------
// AttentionHead: Q/K/V projection (bf16x3 MFMA) + MFMA flash attention
// (swapped-QK^T, in-register softmax+dropout, PV via V^T LDS) + key-compaction.
//
// HISTORY: r6 PASS fp32 pipeline (1184us). r8 PASS qkv->MFMA (847us, absmax
// 4.9e-4 unchanged -> m89 frag layout + bf16x3 HW-validated).
// r9: attn -> MFMA. Swapped QK^T: S = mfma(A=K, B=Q) -> D[key][q], lane holds
// q=l&15, keys (l>>4)*4+r -- which IS the PV A-frag layout (m=q, k=keys).
// Softmax: shfl_xor(16,32) over key-groups; dropout element-local; P packed
// bf16 in-reg; PV = mfma(P, V^T-frag). l = PRE-dropout sums. QK bf16x3;
// P,V single bf16 (error ~1e-4 << 2.75e-3 threshold).
// Fallback: USE_ATTN_MFMA 0 -> r6/r8-validated fp32 attn_fwd.
#define PRNG_VARIANT 2
#define USE_COMPACTION 1
#define USE_ATTN_MFMA 1
// ---------------------------------------------------------------------------

#define B_ 16
#define S_ 2048
#define D_ 1024
#define H_ 128
#define SCALE_ 0.08838834764831845f  /* 1/sqrt(128) */
#define KEEPP_ 0.7f

typedef __attribute__((ext_vector_type(8))) short bf16x8_t;
typedef __attribute__((ext_vector_type(4))) float f32x4_t;

__device__ __forceinline__ void threefry2x32(uint32_t x0, uint32_t x1,
                                             uint32_t& o0, uint32_t& o1) {
  // key = (0, 42); ks2 = 0 ^ 42 ^ 0x1BD11BDA
  const uint32_t ks0 = 0u, ks1 = 42u, ks2 = 0x1BD11BF0u;
  x0 += ks0; x1 += ks1;
#define TF_R(r) { x0 += x1; x1 = (x1 << (r)) | (x1 >> (32 - (r))); x1 ^= x0; }
  TF_R(13) TF_R(15) TF_R(26) TF_R(6)
  x0 += ks1; x1 += ks2 + 1u;
  TF_R(17) TF_R(29) TF_R(16) TF_R(24)
  x0 += ks2; x1 += ks0 + 2u;
  TF_R(13) TF_R(15) TF_R(26) TF_R(6)
  x0 += ks0; x1 += ks1 + 3u;
  TF_R(17) TF_R(29) TF_R(16) TF_R(24)
  x0 += ks1; x1 += ks2 + 4u;
  TF_R(13) TF_R(15) TF_R(26) TF_R(6)
  x0 += ks2; x1 += ks0 + 5u;
#undef TF_R
  o0 = x0; o1 = x1;
}

__device__ __forceinline__ bool keep_rand(uint32_t n) {
  uint32_t o0, o1, bits;
#if PRNG_VARIANT == 2
  threefry2x32(0u, n, o0, o1);
  bits = o0 ^ o1;               // partitionable 32-bit fold (VERIFIED r6/r8)
#elif PRNG_VARIANT == 1
  threefry2x32(0u, n, o0, o1);
  bits = o1;                    // FAILED r5
#else
  if (n < (1u << 25)) { threefry2x32(n, n + (1u << 25), o0, o1); bits = o0; }
  else                { threefry2x32(n - (1u << 25), n, o0, o1); bits = o1; }
#endif
  float u = __uint_as_float((bits >> 9) | 0x3F800000u) - 1.0f;
  return u < KEEPP_;
}

// round-to-nearest-even fp32 -> bf16 (finite inputs)
__device__ __forceinline__ uint16_t bf16_rne(float f) {
  uint32_t u = __float_as_uint(f);
  return (uint16_t)((u + 0x7FFFu + ((u >> 16) & 1u)) >> 16);
}

// frag load: two uint2 at (base + off0), (base + off1) -> bf16x8
__device__ __forceinline__ bf16x8_t ldf(const ushort* base, int off0, int off1) {
  union { uint2 d[2]; bf16x8_t v; } u;
  u.d[0] = *(const uint2*)(base + off0);
  u.d[1] = *(const uint2*)(base + off1);
  return u.v;
}

// ---------------------------------------------------------------------------
// Kernel 0: per-batch compaction of unmasked key indices (unchanged).
// ---------------------------------------------------------------------------
__global__ __launch_bounds__(64) void mask_scan(
    const int* __restrict__ amask,
    int* __restrict__ kidx, int* __restrict__ ncomp) {
  const int b = blockIdx.x;
  const int lane = threadIdx.x;
  const int* m = amask + b * S_;
  int* outp = kidx + b * S_;
  int base = 0;
  for (int c = 0; c < S_; c += 64) {
    const int mv = m[c + lane];
    const unsigned long long bal = __ballot(mv != 0);
    const int off = __popcll(bal & ((1ull << lane) - 1ull));
    if (mv != 0) outp[base + off] = c + lane;
    base += (int)__popcll(bal);
  }
  if (lane == 0) ncomp[b] = base;
  for (int i = base + lane; i < S_; i += 64) outp[i] = 0;
}

// ---------------------------------------------------------------------------
// Kernel 1: qkv projection via bf16x3 MFMA (UNCHANGED from r8 PASS).
// ---------------------------------------------------------------------------
__device__ __forceinline__ bf16x8_t ld_frag(const ushort T[128][36], int row, int g) {
  union { uint2 d[2]; bf16x8_t v; } u;
  u.d[0] = *(const uint2*)&T[row][g << 2];
  u.d[1] = *(const uint2*)&T[row][16 + (g << 2)];
  return u.v;
}

__global__ __launch_bounds__(256) void qkv_mfma(
    const float* __restrict__ x,
    const float* __restrict__ qw, const float* __restrict__ qb,
    const float* __restrict__ kw, const float* __restrict__ kb,
    const float* __restrict__ vw, const float* __restrict__ vb,
    float* __restrict__ qkv) {
  __shared__ ushort Xh[128][36], Xl[128][36], Wh[128][36], Wl[128][36];

  const int tid = threadIdx.x;
  const int m0  = blockIdx.x * 128;
  const int by  = blockIdx.y;
  const float* wsrc = (by == 0) ? qw : (by == 1) ? kw : vw;
  const float* bias = (by == 0) ? qb : (by == 1) ? kb : vb;

  const int wid = tid >> 6, lane = tid & 63;
  const int wy = wid >> 1, wx = wid & 1;
  const int lm = lane & 15, g = lane >> 4;

  const int srow = tid >> 3;
  const int sc4  = (tid & 7) << 2;

  f32x4_t acc[4][4];
#pragma unroll
  for (int i = 0; i < 4; ++i)
#pragma unroll
    for (int j = 0; j < 4; ++j) acc[i][j] = (f32x4_t){0.f, 0.f, 0.f, 0.f};

  for (int k0 = 0; k0 < D_; k0 += 32) {
    __syncthreads();
#pragma unroll
    for (int i = 0; i < 4; ++i) {
      const int row = srow + (i << 5);
      {
        float4 v = *(const float4*)(x + (size_t)(m0 + row) * D_ + k0 + sc4);
        uint16_t h0 = bf16_rne(v.x), h1 = bf16_rne(v.y),
                 h2 = bf16_rne(v.z), h3 = bf16_rne(v.w);
        float r0 = v.x - __uint_as_float((uint32_t)h0 << 16);
        float r1 = v.y - __uint_as_float((uint32_t)h1 << 16);
        float r2 = v.z - __uint_as_float((uint32_t)h2 << 16);
        float r3 = v.w - __uint_as_float((uint32_t)h3 << 16);
        *(uint2*)&Xh[row][sc4] = make_uint2((uint32_t)h0 | ((uint32_t)h1 << 16),
                                            (uint32_t)h2 | ((uint32_t)h3 << 16));
        *(uint2*)&Xl[row][sc4] = make_uint2(
            (uint32_t)bf16_rne(r0) | ((uint32_t)bf16_rne(r1) << 16),
            (uint32_t)bf16_rne(r2) | ((uint32_t)bf16_rne(r3) << 16));
      }
      {
        float4 v = *(const float4*)(wsrc + (size_t)row * D_ + k0 + sc4);
        uint16_t h0 = bf16_rne(v.x), h1 = bf16_rne(v.y),
                 h2 = bf16_rne(v.z), h3 = bf16_rne(v.w);
        float r0 = v.x - __uint_as_float((uint32_t)h0 << 16);
        float r1 = v.y - __uint_as_float((uint32_t)h1 << 16);
        float r2 = v.z - __uint_as_float((uint32_t)h2 << 16);
        float r3 = v.w - __uint_as_float((uint32_t)h3 << 16);
        *(uint2*)&Wh[row][sc4] = make_uint2((uint32_t)h0 | ((uint32_t)h1 << 16),
                                            (uint32_t)h2 | ((uint32_t)h3 << 16));
        *(uint2*)&Wl[row][sc4] = make_uint2(
            (uint32_t)bf16_rne(r0) | ((uint32_t)bf16_rne(r1) << 16),
            (uint32_t)bf16_rne(r2) | ((uint32_t)bf16_rne(r3) << 16));
      }
    }
    __syncthreads();

    bf16x8_t Ah[4], Al[4], Bh[4], Bl[4];
#pragma unroll
    for (int mi = 0; mi < 4; ++mi) {
      const int r = (wy << 6) + (mi << 4) + lm;
      Ah[mi] = ld_frag(Xh, r, g);
      Al[mi] = ld_frag(Xl, r, g);
    }
#pragma unroll
    for (int ni = 0; ni < 4; ++ni) {
      const int r = (wx << 6) + (ni << 4) + lm;
      Bh[ni] = ld_frag(Wh, r, g);
      Bl[ni] = ld_frag(Wl, r, g);
    }
#pragma unroll
    for (int mi = 0; mi < 4; ++mi)
#pragma unroll
      for (int ni = 0; ni < 4; ++ni) {
        acc[mi][ni] = __builtin_amdgcn_mfma_f32_16x16x32_bf16(
            Ah[mi], Bh[ni], acc[mi][ni], 0, 0, 0);
        acc[mi][ni] = __builtin_amdgcn_mfma_f32_16x16x32_bf16(
            Ah[mi], Bl[ni], acc[mi][ni], 0, 0, 0);
        acc[mi][ni] = __builtin_amdgcn_mfma_f32_16x16x32_bf16(
            Al[mi], Bh[ni], acc[mi][ni], 0, 0, 0);
      }
  }

#pragma unroll
  for (int mi = 0; mi < 4; ++mi) {
    const int row = m0 + (wy << 6) + (mi << 4) + (g << 2);
#pragma unroll
    for (int ni = 0; ni < 4; ++ni) {
      const int nl = (wx << 6) + (ni << 4) + lm;
      const float bv = bias[nl];
#pragma unroll
      for (int r = 0; r < 4; ++r)
        qkv[(size_t)(row + r) * 384 + (by << 7) + nl] = acc[mi][ni][r] + bv;
    }
  }
}

// ---------------------------------------------------------------------------
// Kernel 2a: MFMA flash attention over compacted keys.
// Block 128 thr = 2 waves; wave w owns 16 q-rows (q0 + 16w + lm).
// Per 32-key tile: swapped QK^T -> lane holds S[key=(l>>4)*4+r][q=l&15] for
// key tiles {0-15},{16-31}; kill by slot>=nc; softmax reduce via
// shfl_xor(16,32); dropout per element (kidx_s original index); P packed to
// bf16 A-frag IN REGISTER (layout identity); PV = mfma(P, V^T-frag) into
// f32x4 acc[8] (D[q=(l>>4)*4+r][h=ht*16+lm]). Rescale/l cross layouts via
// __shfl(., 4g+r). LDS: Kh/Kl[32][132], Vt[128][36], kidx_s = 25.6 KB.
// ---------------------------------------------------------------------------
__global__ __launch_bounds__(128) void attn_mfma(
    const float* __restrict__ qkv,
    const int* __restrict__ kidx,
    const int* __restrict__ ncomp,
    float* __restrict__ out) {
  __shared__ ushort KhS[32][132], KlS[32][132];
  __shared__ ushort Vt[128][36];
  __shared__ int kidx_s[32];

  const int b   = blockIdx.y;
  const int q0  = blockIdx.x * 32;
  const int tid = threadIdx.x;
  const int wid = tid >> 6, lane = tid & 63;
  const int g = lane >> 4, lm = lane & 15;
  const int nc = ncomp[b];
  const int* kidx_b = kidx + b * S_;
  const int qrow = q0 + wid * 16 + lm;   // softmax-side q of this lane

  // hoist Q B-frags (pre-scaled, hi/lo split). B-frag: n=lm, k={4g..,16+4g..}
  bf16x8_t Qh[4], Ql[4];
  {
    const float* qptr = qkv + (size_t)(b * S_ + qrow) * 384;
#pragma unroll
    for (int c = 0; c < 4; ++c) {
      float4 ea = *(const float4*)(qptr + 32 * c + 4 * g);
      float4 eb = *(const float4*)(qptr + 32 * c + 16 + 4 * g);
      float f[8] = {ea.x, ea.y, ea.z, ea.w, eb.x, eb.y, eb.z, eb.w};
      union { ushort u[8]; bf16x8_t v; } hh, ll;
#pragma unroll
      for (int e = 0; e < 8; ++e) {
        float s = f[e] * SCALE_;
        ushort h = bf16_rne(s);
        hh.u[e] = h;
        ll.u[e] = bf16_rne(s - __uint_as_float((uint32_t)h << 16));
      }
      Qh[c] = hh.v; Ql[c] = ll.v;
    }
  }

  f32x4_t acc[8];
#pragma unroll
  for (int t = 0; t < 8; ++t) acc[t] = (f32x4_t){0.f, 0.f, 0.f, 0.f};
  float m_run = -INFINITY, l_run = 0.f;
  const uint32_t nq = (uint32_t)(b * S_ + qrow) << 11;

  for (int kt = 0; kt < nc; kt += 32) {
    __syncthreads();   // prev tile's frag reads done
    if (tid < 32) kidx_s[tid] = kidx_b[kt + tid];
    // stage K (hi/lo split)
#pragma unroll
    for (int i = 0; i < 8; ++i) {
      int flat = i * 128 + tid;
      int key = flat >> 5, c4 = (flat & 31) << 2;
      int krow = kidx_b[kt + key];
      float4 v = *(const float4*)(qkv + ((size_t)(b * S_ + krow) * 384 + 128) + c4);
      uint16_t h0 = bf16_rne(v.x), h1 = bf16_rne(v.y),
               h2 = bf16_rne(v.z), h3 = bf16_rne(v.w);
      float r0 = v.x - __uint_as_float((uint32_t)h0 << 16);
      float r1 = v.y - __uint_as_float((uint32_t)h1 << 16);
      float r2 = v.z - __uint_as_float((uint32_t)h2 << 16);
      float r3 = v.w - __uint_as_float((uint32_t)h3 << 16);
      *(uint2*)&KhS[key][c4] = make_uint2((uint32_t)h0 | ((uint32_t)h1 << 16),
                                          (uint32_t)h2 | ((uint32_t)h3 << 16));
      *(uint2*)&KlS[key][c4] = make_uint2(
          (uint32_t)bf16_rne(r0) | ((uint32_t)bf16_rne(r1) << 16),
          (uint32_t)bf16_rne(r2) | ((uint32_t)bf16_rne(r3) << 16));
    }
    // stage V^T (single bf16)
#pragma unroll
    for (int i = 0; i < 8; ++i) {
      int flat = i * 128 + tid;
      int key = flat >> 5, c4 = (flat & 31) << 2;
      int krow = kidx_b[kt + key];
      float4 v = *(const float4*)(qkv + ((size_t)(b * S_ + krow) * 384 + 256) + c4);
      Vt[c4 + 0][key] = bf16_rne(v.x);
      Vt[c4 + 1][key] = bf16_rne(v.y);
      Vt[c4 + 2][key] = bf16_rne(v.z);
      Vt[c4 + 3][key] = bf16_rne(v.w);
    }
    __syncthreads();

    // swapped QK^T: s0 = keys 0-15, s1 = keys 16-31 (bf16x3)
    f32x4_t s0 = (f32x4_t){0.f, 0.f, 0.f, 0.f};
    f32x4_t s1 = (f32x4_t){0.f, 0.f, 0.f, 0.f};
#pragma unroll
    for (int c = 0; c < 4; ++c) {
      const int o0 = 32 * c + 4 * g, o1 = 32 * c + 16 + 4 * g;
      bf16x8_t a0h = ldf(&KhS[lm][0], o0, o1);
      bf16x8_t a0l = ldf(&KlS[lm][0], o0, o1);
      bf16x8_t a1h = ldf(&KhS[lm + 16][0], o0, o1);
      bf16x8_t a1l = ldf(&KlS[lm + 16][0], o0, o1);
      s0 = __builtin_amdgcn_mfma_f32_16x16x32_bf16(a0h, Qh[c], s0, 0, 0, 0);
      s0 = __builtin_amdgcn_mfma_f32_16x16x32_bf16(a0l, Qh[c], s0, 0, 0, 0);
      s0 = __builtin_amdgcn_mfma_f32_16x16x32_bf16(a0h, Ql[c], s0, 0, 0, 0);
      s1 = __builtin_amdgcn_mfma_f32_16x16x32_bf16(a1h, Qh[c], s1, 0, 0, 0);
      s1 = __builtin_amdgcn_mfma_f32_16x16x32_bf16(a1l, Qh[c], s1, 0, 0, 0);
      s1 = __builtin_amdgcn_mfma_f32_16x16x32_bf16(a1h, Ql[c], s1, 0, 0, 0);
    }

    // kill tail slots, online softmax (lane owns q=lm; keys 4g+r, 16+4g+r)
    float sv0[4], sv1[4];
#pragma unroll
    for (int r = 0; r < 4; ++r) {
      sv0[r] = (kt + 4 * g + r      < nc) ? s0[r] : -INFINITY;
      sv1[r] = (kt + 16 + 4 * g + r < nc) ? s1[r] : -INFINITY;
    }
    float tm = fmaxf(fmaxf(fmaxf(sv0[0], sv0[1]), fmaxf(sv0[2], sv0[3])),
                     fmaxf(fmaxf(sv1[0], sv1[1]), fmaxf(sv1[2], sv1[3])));
    tm = fmaxf(tm, __shfl_xor(tm, 16));
    tm = fmaxf(tm, __shfl_xor(tm, 32));
    float mn = fmaxf(m_run, tm);

    float p0[4], p1[4], ps = 0.f;
#pragma unroll
    for (int r = 0; r < 4; ++r) {
      p0[r] = (sv0[r] == -INFINITY) ? 0.f : __expf(sv0[r] - mn);
      p1[r] = (sv1[r] == -INFINITY) ? 0.f : __expf(sv1[r] - mn);
      ps += p0[r] + p1[r];
    }
    ps += __shfl_xor(ps, 16);
    ps += __shfl_xor(ps, 32);

    float rf = (m_run == mn) ? 1.f : __expf(m_run - mn);
    l_run = l_run * rf + ps;
    m_run = mn;

    // rescale acc (acc rows are q = 4g+r -> fetch those q's factors)
    float fr0 = __shfl(rf, 4 * g + 0);
    float fr1 = __shfl(rf, 4 * g + 1);
    float fr2 = __shfl(rf, 4 * g + 2);
    float fr3 = __shfl(rf, 4 * g + 3);
#pragma unroll
    for (int t = 0; t < 8; ++t) {
      acc[t][0] *= fr0; acc[t][1] *= fr1; acc[t][2] *= fr2; acc[t][3] *= fr3;
    }

    // dropout (original key index) + pack P as bf16 A-frag
    union { ushort u[8]; bf16x8_t v; } pk;
#pragma unroll
    for (int r = 0; r < 4; ++r) {
      float dv0 = keep_rand(nq + (uint32_t)kidx_s[4 * g + r])      ? p0[r] : 0.f;
      float dv1 = keep_rand(nq + (uint32_t)kidx_s[16 + 4 * g + r]) ? p1[r] : 0.f;
      pk.u[r]     = bf16_rne(dv0);
      pk.u[4 + r] = bf16_rne(dv1);
    }

    // PV: acc[ht] += P * V  (D[q=(l>>4)*4+r][h=ht*16+lm])
#pragma unroll
    for (int ht = 0; ht < 8; ++ht) {
      bf16x8_t vf = ldf(&Vt[ht * 16 + lm][0], 4 * g, 16 + 4 * g);
      acc[ht] = __builtin_amdgcn_mfma_f32_16x16x32_bf16(pk.v, vf, acc[ht], 0, 0, 0);
    }
  }

  // epilogue: normalize by this acc-row's l (cross-layout via shfl)
  float iv[4];
#pragma unroll
  for (int r = 0; r < 4; ++r) {
    float lq = __shfl(l_run, 4 * g + r);
    iv[r] = 1.0f / (lq * KEEPP_);
  }
#pragma unroll
  for (int ht = 0; ht < 8; ++ht) {
#pragma unroll
    for (int r = 0; r < 4; ++r) {
      const int q = q0 + wid * 16 + 4 * g + r;
      out[(size_t)(b * S_ + q) * H_ + ht * 16 + lm] = acc[ht][r] * iv[r];
    }
  }
}

#if !USE_ATTN_MFMA
// ---------------------------------------------------------------------------
// Kernel 2b: fp32 flash attention (r6/r8-validated fallback).
// ---------------------------------------------------------------------------
__global__ __launch_bounds__(256) void attn_fwd(
    const float* __restrict__ qkv,
    const int* __restrict__ kidx,
    const int* __restrict__ ncomp,
    float* __restrict__ out) {
  __shared__ float Qs[32][132];
  __shared__ float Ks[32][132];

  const int b   = blockIdx.y;
  const int q0  = blockIdx.x * 32;
  const int tid = threadIdx.x;
  const int ty = tid >> 4, tx = tid & 15;
  const int nc = ncomp[b];
  const int* kidx_b = kidx + b * S_;

  const float* qbase = qkv + (size_t)(b * S_ + q0) * 384;
#pragma unroll
  for (int rep = 0; rep < 4; ++rep) {
    int idx = rep * 256 + tid;
    int r = idx >> 5, c4 = (idx & 31) << 2;
    float4 v = *(const float4*)(qbase + (size_t)r * 384 + c4);
    v.x *= SCALE_; v.y *= SCALE_; v.z *= SCALE_; v.w *= SCALE_;
    *(float4*)&Qs[r][c4] = v;
  }

  const int qr = ty * 2;
  const int hx = tx * 8;

  float acc0[8], acc1[8];
#pragma unroll
  for (int h = 0; h < 8; ++h) { acc0[h] = 0.f; acc1[h] = 0.f; }
  float m0v = -INFINITY, m1v = -INFINITY, l0 = 0.f, l1 = 0.f;

  const uint32_t nq0 = (uint32_t)(b * S_ + q0 + qr) << 11;
  const uint32_t nq1 = nq0 + (1u << 11);

  for (int kt = 0; kt < nc; kt += 32) {
    __syncthreads();
#pragma unroll
    for (int rep = 0; rep < 4; ++rep) {
      int idx = rep * 256 + tid;
      int r = idx >> 5, c4 = (idx & 31) << 2;
      int krow = kidx_b[kt + r];
      *(float4*)&Ks[r][c4] =
          *(const float4*)(qkv + ((size_t)(b * S_ + krow) * 384 + 128) + c4);
    }
    const int j0 = kt + tx, j1 = j0 + 16;
    const int kr0 = kidx_b[j0];
    const int kr1 = kidx_b[j1];
    const bool kill0 = (j0 >= nc), kill1 = (j1 >= nc);
    __syncthreads();

    float s00 = 0.f, s01 = 0.f, s10 = 0.f, s11 = 0.f;
#pragma unroll 8
    for (int d = 0; d < 128; d += 4) {
      float4 qv0 = *(const float4*)&Qs[qr][d];
      float4 qv1 = *(const float4*)&Qs[qr + 1][d];
      float4 kv0 = *(const float4*)&Ks[tx][d];
      float4 kv1 = *(const float4*)&Ks[tx + 16][d];
      s00 += qv0.x * kv0.x + qv0.y * kv0.y + qv0.z * kv0.z + qv0.w * kv0.w;
      s01 += qv0.x * kv1.x + qv0.y * kv1.y + qv0.z * kv1.z + qv0.w * kv1.w;
      s10 += qv1.x * kv0.x + qv1.y * kv0.y + qv1.z * kv0.z + qv1.w * kv0.w;
      s11 += qv1.x * kv1.x + qv1.y * kv1.y + qv1.z * kv1.z + qv1.w * kv1.w;
    }
    if (kill0) { s00 = -INFINITY; s10 = -INFINITY; }
    if (kill1) { s01 = -INFINITY; s11 = -INFINITY; }

    float tm0 = fmaxf(s00, s01);
    float tm1 = fmaxf(s10, s11);
#pragma unroll
    for (int o = 1; o < 16; o <<= 1) {
      tm0 = fmaxf(tm0, __shfl_xor(tm0, o, 16));
      tm1 = fmaxf(tm1, __shfl_xor(tm1, o, 16));
    }
    float mn0 = fmaxf(m0v, tm0);
    float mn1 = fmaxf(m1v, tm1);

    float p00 = (s00 == -INFINITY) ? 0.f : __expf(s00 - mn0);
    float p01 = (s01 == -INFINITY) ? 0.f : __expf(s01 - mn0);
    float p10 = (s10 == -INFINITY) ? 0.f : __expf(s10 - mn1);
    float p11 = (s11 == -INFINITY) ? 0.f : __expf(s11 - mn1);

    float ps0 = p00 + p01, ps1 = p10 + p11;
#pragma unroll
    for (int o = 1; o < 16; o <<= 1) {
      ps0 += __shfl_xor(ps0, o, 16);
      ps1 += __shfl_xor(ps1, o, 16);
    }

    float r0 = (m0v == mn0) ? 1.f : __expf(m0v - mn0);
    float r1 = (m1v == mn1) ? 1.f : __expf(m1v - mn1);
    l0 = l0 * r0 + ps0;
    l1 = l1 * r1 + ps1;
#pragma unroll
    for (int h = 0; h < 8; ++h) { acc0[h] *= r0; acc1[h] *= r1; }
    m0v = mn0; m1v = mn1;

    float d00 = keep_rand(nq0 + (uint32_t)kr0) ? p00 : 0.f;
    float d01 = keep_rand(nq0 + (uint32_t)kr1) ? p01 : 0.f;
    float d10 = keep_rand(nq1 + (uint32_t)kr0) ? p10 : 0.f;
    float d11 = keep_rand(nq1 + (uint32_t)kr1) ? p11 : 0.f;

    const float* vb_ = qkv + ((size_t)b * S_) * 384 + 256 + hx;
#pragma unroll 8
    for (int k = 0; k < 16; ++k) {
      float pa = __shfl(d00, k, 16);
      float pb = __shfl(d10, k, 16);
      int vrow = __shfl(kr0, k, 16);
      const float* vr = vb_ + (size_t)vrow * 384;
      float4 va  = *(const float4*)(vr);
      float4 vb2 = *(const float4*)(vr + 4);
      acc0[0] += pa * va.x;  acc0[1] += pa * va.y;
      acc0[2] += pa * va.z;  acc0[3] += pa * va.w;
      acc0[4] += pa * vb2.x; acc0[5] += pa * vb2.y;
      acc0[6] += pa * vb2.z; acc0[7] += pa * vb2.w;
      acc1[0] += pb * va.x;  acc1[1] += pb * va.y;
      acc1[2] += pb * va.z;  acc1[3] += pb * va.w;
      acc1[4] += pb * vb2.x; acc1[5] += pb * vb2.y;
      acc1[6] += pb * vb2.z; acc1[7] += pb * vb2.w;
    }
#pragma unroll 8
    for (int k = 0; k < 16; ++k) {
      float pa = __shfl(d01, k, 16);
      float pb = __shfl(d11, k, 16);
      int vrow = __shfl(kr1, k, 16);
      const float* vr = vb_ + (size_t)vrow * 384;
      float4 va  = *(const float4*)(vr);
      float4 vb2 = *(const float4*)(vr + 4);
      acc0[0] += pa * va.x;  acc0[1] += pa * va.y;
      acc0[2] += pa * va.z;  acc0[3] += pa * va.w;
      acc0[4] += pa * vb2.x; acc0[5] += pa * vb2.y;
      acc0[6] += pa * vb2.z; acc0[7] += pa * vb2.w;
      acc1[0] += pb * va.x;  acc1[1] += pb * va.y;
      acc1[2] += pb * va.z;  acc1[3] += pb * va.w;
      acc1[4] += pb * vb2.x; acc1[5] += pb * vb2.y;
      acc1[6] += pb * vb2.z; acc1[7] += pb * vb2.w;
    }
  }

  const float inv0 = 1.0f / (l0 * KEEPP_);
  const float inv1 = 1.0f / (l1 * KEEPP_);
  float* o0 = out + (size_t)(b * S_ + q0 + qr) * H_ + hx;
  float* o1 = o0 + H_;
  float4 w0 = make_float4(acc0[0] * inv0, acc0[1] * inv0, acc0[2] * inv0, acc0[3] * inv0);
  float4 w1 = make_float4(acc0[4] * inv0, acc0[5] * inv0, acc0[6] * inv0, acc0[7] * inv0);
  float4 w2 = make_float4(acc1[0] * inv1, acc1[1] * inv1, acc1[2] * inv1, acc1[3] * inv1);
  float4 w3 = make_float4(acc1[4] * inv1, acc1[5] * inv1, acc1[6] * inv1, acc1[7] * inv1);
  *(float4*)(o0)     = w0;
  *(float4*)(o0 + 4) = w1;
  *(float4*)(o1)     = w2;
  *(float4*)(o1 + 4) = w3;
}
#endif

// ---------------------------------------------------------------------------
extern "C" void kernel_launch(void* const* d_in, const int* in_sizes, int n_in,
                              void* d_out, int out_size, void* d_ws, size_t ws_size,
                              hipStream_t stream) {
  (void)in_sizes; (void)n_in; (void)out_size; (void)ws_size;
  const float* x  = (const float*)d_in[0];
  const int* am   = (const int*)d_in[1];
  const float* qw = (const float*)d_in[2];
  const float* qb = (const float*)d_in[3];
  const float* kw = (const float*)d_in[4];
  const float* kb = (const float*)d_in[5];
  const float* vw = (const float*)d_in[6];
  const float* vb = (const float*)d_in[7];
  float* out = (float*)d_out;

  // ws layout: qkv (48MB) | kidx (16*2048*4) | ncomp (16*4)
  float* qkv = (float*)d_ws;
  int* kidx  = (int*)((char*)d_ws + (size_t)B_ * S_ * 384 * 4);
  int* ncomp = kidx + B_ * S_;

  mask_scan<<<B_, 64, 0, stream>>>(am, kidx, ncomp);
  qkv_mfma<<<dim3((B_ * S_) / 128, 3), 256, 0, stream>>>(
      x, qw, qb, kw, kb, vw, vb, qkv);
#if USE_ATTN_MFMA
  attn_mfma<<<dim3(S_ / 32, B_), 128, 0, stream>>>(qkv, kidx, ncomp, out);
#else
  attn_fwd<<<dim3(S_ / 32, B_), 256, 0, stream>>>(qkv, kidx, ncomp, out);
#endif
}